// Round 6
// baseline (181.583 us; speedup 1.0000x reference)
//
#include <hip/hip_runtime.h>
#include <hip/hip_bf16.h>

#define NN 50000
#define DD 64
#define EE 800000
#define NB 196      // ceil(NN/256) scan blocks
#define NTILE 3125  // NN/16 row tiles (exact)
#define NBLKL 391   // ceil(NTILE/8) linear blocks (8 tiles/block, 2/wave)
#define NSLICE 128  // edge slices for scatter
#define ESL 6250    // EE/NSLICE edges per slice
#define DRNG 6250   // NN/8 dst nodes per XCD range

typedef unsigned short u16;
typedef unsigned int u32;
typedef __attribute__((ext_vector_type(8))) short bf16x8;
typedef __attribute__((ext_vector_type(4))) float f32x4;

__device__ __forceinline__ float bf2f(u16 u) {
  u32 t = ((u32)u) << 16;
  return __builtin_bit_cast(float, t);
}
__device__ __forceinline__ u16 f2bf(float f) {
  u32 b = __builtin_bit_cast(u32, f);
  u32 r = (b + 0x7FFF + ((b >> 16) & 1)) >> 16;
  return (u16)r;
}

// ---------------------------------------------------------------------------
// Kernel 1 (MFMA): x = nf @ W.T + b_lin, bf16 out. Also zeroes cnt[].
// 2 row-tiles per wave (8 per block): halves W-staging re-reads vs 1/wave.
// C/D mapping: col=lane&15, row=(lane>>4)*4+reg  [verified m89/m91]
// ---------------------------------------------------------------------------
__global__ __launch_bounds__(256) void linear_mfma_kernel(
    const float* __restrict__ nf, const float* __restrict__ W,
    const float* __restrict__ b_lin, u16* __restrict__ x16,
    int* __restrict__ cnt) {
  __shared__ u16 Wsh[64 * 72];
  int tid = threadIdx.x;

  // fold hist-counter zeroing into this dispatch (NBLKL=391 >= NB=196)
  if (blockIdx.x < NB) {
    int zi = blockIdx.x * 256 + tid;
    if (zi < NN) cnt[zi] = 0;
  }

#pragma unroll
  for (int s = 0; s < 16; ++s) {
    int idx = s * 256 + tid;
    int j = idx >> 6, k = idx & 63;
    Wsh[j * 72 + k] = f2bf(W[idx]);
  }
  __syncthreads();

  int wave = tid >> 6;
  int lane = tid & 63;
  int m = lane & 15;
  int quad = lane >> 4;

  bf16x8 bfrag[4][2];
#pragma unroll
  for (int c = 0; c < 4; ++c) {
#pragma unroll
    for (int ks = 0; ks < 2; ++ks) {
      const u16* p = &Wsh[(c * 16 + m) * 72 + ks * 32 + quad * 8];
      bfrag[c][ks] = *(const bf16x8*)p;
    }
  }

#pragma unroll
  for (int tt = 0; tt < 2; ++tt) {
    int tile = blockIdx.x * 8 + wave * 2 + tt;
    if (tile >= NTILE) continue;  // tail block only
    int rowbase = tile * 16;

    bf16x8 afrag[2];
#pragma unroll
    for (int ks = 0; ks < 2; ++ks) {
      const float* p = nf + (rowbase + m) * DD + ks * 32 + quad * 8;
      float4 lo = *(const float4*)p;
      float4 hi = *(const float4*)(p + 4);
      bf16x8 a;
      a[0] = (short)f2bf(lo.x); a[1] = (short)f2bf(lo.y);
      a[2] = (short)f2bf(lo.z); a[3] = (short)f2bf(lo.w);
      a[4] = (short)f2bf(hi.x); a[5] = (short)f2bf(hi.y);
      a[6] = (short)f2bf(hi.z); a[7] = (short)f2bf(hi.w);
      afrag[ks] = a;
    }

    f32x4 acc[4];
#pragma unroll
    for (int c = 0; c < 4; ++c) {
      acc[c][0] = 0.0f; acc[c][1] = 0.0f; acc[c][2] = 0.0f; acc[c][3] = 0.0f;
    }
#pragma unroll
    for (int c = 0; c < 4; ++c) {
      acc[c] = __builtin_amdgcn_mfma_f32_16x16x32_bf16(afrag[0], bfrag[c][0], acc[c], 0, 0, 0);
      acc[c] = __builtin_amdgcn_mfma_f32_16x16x32_bf16(afrag[1], bfrag[c][1], acc[c], 0, 0, 0);
    }

#pragma unroll
    for (int c = 0; c < 4; ++c) {
      int gcol = c * 16 + m;
      float bl = b_lin[gcol];
#pragma unroll
      for (int r = 0; r < 4; ++r) {
        int grow = rowbase + quad * 4 + r;
        x16[grow * DD + gcol] = f2bf(acc[c][r] + bl);
      }
    }
  }
}

// ---------------------------------------------------------------------------
// hist: 4 edges per thread (two int4 loads), atomic per-dst counts.
// ---------------------------------------------------------------------------
__global__ __launch_bounds__(256) void hist_kernel(
    const int* __restrict__ ei, int* __restrict__ cnt) {
  int e = (blockIdx.x * 256 + threadIdx.x) * 4;
  if (e >= EE) return;
  int4 a = *(const int4*)(ei + 2 * e);
  int4 b = *(const int4*)(ei + 2 * e + 4);
  atomicAdd(&cnt[a.y], 1);
  atomicAdd(&cnt[a.w], 1);
  atomicAdd(&cnt[b.y], 1);
  atomicAdd(&cnt[b.w], 1);
}

// ---------------------------------------------------------------------------
// scan1: per-block sums of cnt -> partial[196]
// ---------------------------------------------------------------------------
__global__ __launch_bounds__(256) void scan1_kernel(
    const int* __restrict__ cnt, int* __restrict__ partial) {
  __shared__ int s[256];
  int t = threadIdx.x;
  int i = blockIdx.x * 256 + t;
  s[t] = (i < NN) ? cnt[i] : 0;
  __syncthreads();
#pragma unroll
  for (int o = 128; o > 0; o >>= 1) {
    if (t < o) s[t] += s[t + o];
    __syncthreads();
  }
  if (t == 0) partial[blockIdx.x] = s[0];
}

// ---------------------------------------------------------------------------
// scan23: each block redundantly scans partial[], then scans its cnt chunk.
// Writes csr_off (exclusive) and cur (= csr_off copy).
// ---------------------------------------------------------------------------
__global__ __launch_bounds__(256) void scan23_kernel(
    const int* __restrict__ cnt, const int* __restrict__ partial,
    int* __restrict__ csr_off, int* __restrict__ cur) {
  __shared__ int sp[256];
  __shared__ int s[256];
  __shared__ int boff;
  int t = threadIdx.x;

  int pv = (t < NB) ? partial[t] : 0;
  sp[t] = pv;
  __syncthreads();
#pragma unroll
  for (int o = 1; o < 256; o <<= 1) {
    int u = (t >= o) ? sp[t - o] : 0;
    __syncthreads();
    sp[t] += u;
    __syncthreads();
  }
  if (t == 0) boff = (blockIdx.x > 0) ? sp[blockIdx.x - 1] : 0;  // exclusive
  __syncthreads();

  int i = blockIdx.x * 256 + t;
  int v = (i < NN) ? cnt[i] : 0;
  s[t] = v;
  __syncthreads();
#pragma unroll
  for (int o = 1; o < 256; o <<= 1) {
    int u = (t >= o) ? s[t - o] : 0;
    __syncthreads();
    s[t] += u;
    __syncthreads();
  }
  int off = boff + s[t] - v;  // exclusive scan of cnt
  if (i < NN) {
    csr_off[i] = off;
    cur[i] = off;
    if (i == NN - 1) csr_off[NN] = off + v;  // == EE
  }
}

// ---------------------------------------------------------------------------
// scatter: XCD-sliced. Block b: dst range r=b&7 (6250 nodes), edge slice
// s=b>>3 (6250 edges). csr_src region + cur counters of a range are written
// by one XCD's blocks (round-robin heuristic; correctness mapping-agnostic).
// ---------------------------------------------------------------------------
__global__ __launch_bounds__(256) void scatter_kernel(
    const int* __restrict__ ei, int* __restrict__ cur,
    u16* __restrict__ csr_src) {
  int r = blockIdx.x & 7;
  int sl = blockIdx.x >> 3;
  int rlo = r * DRNG;
  int ebase = sl * ESL;
  int eend = ebase + ESL;
#pragma unroll 1
  for (int it = 0; it < 13; ++it) {
    int e = ebase + it * 512 + (int)threadIdx.x * 2;
    if (e < eend) {
      int4 p = *(const int4*)(ei + 2 * e);  // (src0,dst0,src1,dst1)
      if ((u32)(p.y - rlo) < (u32)DRNG) {
        int pos = atomicAdd(&cur[p.y], 1);
        csr_src[pos] = (u16)p.x;
      }
      if ((u32)(p.w - rlo) < (u32)DRNG) {
        int pos = atomicAdd(&cur[p.w], 1);
        csr_src[pos] = (u16)p.z;
      }
    }
  }
}

// ---------------------------------------------------------------------------
// gather: one wave per node. One coalesced 128 B load grabs 64 csr_src
// entries; readlane (SGPR lane idx) broadcasts each so row loads issue
// independently (MLP = deg). Lanes k >= win are CLAMPED to the last valid
// edge (k=win-1): the duplicate row is already in-flight/L1, so waste loads
// cost ~0 instead of a random L3 row. Their contribution is cndmask-gated.
// beg/end readfirstlane'd so all loop control + clamps stay scalar.
// ---------------------------------------------------------------------------
__device__ __forceinline__ void loadchunk(int my, int win, int base,
                                          const u16* __restrict__ x16, int j,
                                          float* v) {
#pragma unroll
  for (int k = 0; k < 16; ++k) {
    int kk = base + k;
    int cl = (kk < win) ? kk : (win - 1);  // scalar clamp
    int s = __builtin_amdgcn_readlane(my, cl);
    v[kk] = bf2f(x16[s * DD + j]);
  }
}
__device__ __forceinline__ float sum16(const float* v, int base, int win) {
  float a = 0.0f;
#pragma unroll
  for (int k = 0; k < 16; ++k) {
    int kk = base + k;
    a += (kk < win) ? v[kk] : 0.0f;
  }
  return a;
}

__global__ __launch_bounds__(256) void gather_kernel(
    const u16* __restrict__ x16, const u16* __restrict__ csr_src,
    const int* __restrict__ csr_off, const float* __restrict__ bias,
    float* __restrict__ out) {
  int i = blockIdx.x * 4 + (threadIdx.x >> 6);  // grid exact: NN/4 blocks
  int j = threadIdx.x & 63;
  int beg = __builtin_amdgcn_readfirstlane(csr_off[i]);
  int end = __builtin_amdgcn_readfirstlane(csr_off[i + 1]);
  float acc = 0.0f;
  int pos = beg;
#pragma unroll 1
  while (pos < end) {  // 1 iteration for deg<=64 (always, in practice)
    int my = (int)csr_src[pos + j];  // csr_src padded by 64 entries
    int win = end - pos;
    win = win > 64 ? 64 : win;
    int nc = (win + 15) >> 4;
    float v[64];
    // all loads first: MLP = win
    loadchunk(my, win, 0, x16, j, v);
    if (nc > 1) loadchunk(my, win, 16, x16, j, v);
    if (nc > 2) loadchunk(my, win, 32, x16, j, v);
    if (nc > 3) loadchunk(my, win, 48, x16, j, v);
    // gated adds after
    acc += sum16(v, 0, win);
    if (nc > 1) acc += sum16(v, 16, win);
    if (nc > 2) acc += sum16(v, 32, win);
    if (nc > 3) acc += sum16(v, 48, win);
    pos += 64;
  }
  float deg = (float)(end - beg);
  float inv = 1.0f / fmaxf(deg, 1.0f);
  float self = bf2f(x16[i * DD + j]);
  out[i * DD + j] = fmaxf(fmaf(acc, inv, self + bias[j]), 0.0f);
}

extern "C" void kernel_launch(void* const* d_in, const int* in_sizes, int n_in,
                              void* d_out, int out_size, void* d_ws, size_t ws_size,
                              hipStream_t stream) {
  const float* nf    = (const float*)d_in[0];
  const int*   ei    = (const int*)d_in[1];
  const float* W     = (const float*)d_in[2];
  const float* b_lin = (const float*)d_in[3];
  const float* bias  = (const float*)d_in[4];
  float* out = (float*)d_out;

  // workspace layout (x16 MUST be at base: gather's clamped garbage reads
  // stay inside [0, 8.4 MB) of d_ws)
  u16* x16     = (u16*)d_ws;                       // N*D bf16   (6.4 MB)
  u16* csr_src = x16 + (size_t)NN * DD;            // E u16 + 64 pad (1.6 MB)
  int* csr_off = (int*)(csr_src + EE + 64);        // N+1 ints
  int* cur     = csr_off + (NN + 1);               // N ints
  int* cnt     = cur + NN;                         // N ints
  int* partial = cnt + NN;                         // NB ints
  // total ~8.6 MB << ws_size

  linear_mfma_kernel<<<NBLKL, 256, 0, stream>>>(nf, W, b_lin, x16, cnt);
  hist_kernel<<<(EE / 4 + 255) / 256, 256, 0, stream>>>(ei, cnt);
  scan1_kernel<<<NB, 256, 0, stream>>>(cnt, partial);
  scan23_kernel<<<NB, 256, 0, stream>>>(cnt, partial, csr_off, cur);
  scatter_kernel<<<NSLICE * 8, 256, 0, stream>>>(ei, cur, csr_src);
  gather_kernel<<<NN / 4, 256, 0, stream>>>(x16, csr_src, csr_off, bias, out);
}